// Round 1
// baseline (2580.248 us; speedup 1.0000x reference)
//
#include <hip/hip_runtime.h>

// SPADE ResNet block, fp32 correctness-first implementation.
// dims: B=4, FIN=64, FOUT=32, FMID=32, NCLS=4, NH=64, S=32 (32^3 = 32768 voxels)
// Pipeline:
//   stats0 = instnorm stats(x)
//   actv0  = relu(conv3(x, s0_ws[y]) + s0_bs[y])
//   h0     = lrelu( norm0(x) * (1 + conv3(actv0, s0_wg[y]) + bg) + conv3(actv0, s0_wb[y]) + bb )
//   dx0    = conv3(h0, conv0_w) + conv0_b
//   stats1 = instnorm stats(dx0)
//   actv1  = relu(conv3(dx0, s1_ws[y]) + s1_bs[y])
//   h1     = lrelu( norm1(dx0) * (1 + conv3(actv1, s1_wg[y]) + bg) + conv3(actv1, s1_wb[y]) + bb )
//   out    = conv1x1(x, convs_w) + conv3(h1, conv1_w) + conv1_b

#define S3 32768
#define SDIM 32
constexpr float EPS = 1e-5f;

// ---------------------------------------------------------------- stats ----
// One block per (b, c): mean + rstd over 32768 voxels.
__global__ __launch_bounds__(256) void stats_kernel(const float* __restrict__ x,
                                                    float* __restrict__ mu,
                                                    float* __restrict__ rstd) {
  const int bc = blockIdx.x;
  const float* p = x + (size_t)bc * S3;
  float s = 0.f, s2 = 0.f;
  for (int i = threadIdx.x; i < S3 / 4; i += 256) {
    float4 v = reinterpret_cast<const float4*>(p)[i];
    s  += v.x + v.y + v.z + v.w;
    s2 += v.x * v.x + v.y * v.y + v.z * v.z + v.w * v.w;
  }
  for (int off = 32; off; off >>= 1) {
    s  += __shfl_down(s, off, 64);
    s2 += __shfl_down(s2, off, 64);
  }
  __shared__ float ls[4], ls2[4];
  const int wid = threadIdx.x >> 6;
  if ((threadIdx.x & 63) == 0) { ls[wid] = s; ls2[wid] = s2; }
  __syncthreads();
  if (threadIdx.x == 0) {
    float S = 0.f, S2 = 0.f;
    for (int i = 0; i < 4; ++i) { S += ls[i]; S2 += ls2[i]; }
    const float m = S / (float)S3;
    const float var = S2 / (float)S3 - m * m;
    mu[bc] = m;
    rstd[bc] = rsqrtf(var + EPS);
  }
}

// ---------------------------------------------------------------- conv3 ----
// Direct 3x3x3 conv, padding 1. Block = 8x8x8 spatial tile, 256 threads,
// 2 voxels/thread, 32 output channels/block (co_base = blockIdx.z*32).
// MODE: 0 = relu(acc+bias) store, 1 = (acc+bias) store, 2 = out += acc+bias.
template <int CIN, int MODE>
__global__ __launch_bounds__(256) void conv3_kernel(
    const float* __restrict__ in,       // [B][CIN][S3]
    const float* __restrict__ wstack,   // [(cls)][NCO][CIN][27]
    long wcls,                          // per-class weight stride (elems), 0 if shared
    const float* __restrict__ bstack,   // [(cls)][NCO]
    long bcls,                          // per-class bias stride
    const int* __restrict__ y,
    float* __restrict__ out,            // [B][nco_total][S3]
    int nco_total) {
  const int tid = threadIdx.x;
  const int b = blockIdx.y;
  const int cls = y[b];
  const int co_base = blockIdx.z * 32;
  const int tile = blockIdx.x;
  const int d0 = (tile >> 4) * 8, h0 = ((tile >> 2) & 3) * 8, w0 = (tile & 3) * 8;
  const int vd = tid >> 6, vh = (tid >> 3) & 7, vw = tid & 7;

  __shared__ float ldsX[4 * 1000];       // 4 cin x 10x10x10 padded tile
  __shared__ float ldsW[4 * 27 * 32];    // [ci][tap][oc]

  float acc0[32], acc1[32];
#pragma unroll
  for (int o = 0; o < 32; ++o) { acc0[o] = 0.f; acc1[o] = 0.f; }

  const float* xin = in + (size_t)b * CIN * S3;
  const float* wbase = wstack + (size_t)wcls * cls + (size_t)co_base * CIN * 27;

  for (int cg = 0; cg < CIN / 4; ++cg) {
    __syncthreads();
    // stage input tiles (zero-padded)
    for (int i = tid; i < 4000; i += 256) {
      int ci = i / 1000, r = i - ci * 1000;
      int dd = r / 100; r -= dd * 100;
      int hh = r / 10;
      int ww = r - hh * 10;
      int gd = d0 + dd - 1, gh = h0 + hh - 1, gw = w0 + ww - 1;
      float v = 0.f;
      if ((unsigned)gd < 32u && (unsigned)gh < 32u && (unsigned)gw < 32u)
        v = xin[(size_t)(cg * 4 + ci) * S3 + gd * 1024 + gh * 32 + gw];
      ldsX[i] = v;
    }
    // stage weights: lds[ci][tap][oc]
    for (int i = tid; i < 4 * 27 * 32; i += 256) {
      int oc = i & 31, ct = i >> 5;
      int ci = ct / 27, t = ct - ci * 27;
      ldsW[i] = wbase[(size_t)oc * CIN * 27 + (size_t)(cg * 4 + ci) * 27 + t];
    }
    __syncthreads();

#pragma unroll
    for (int ci = 0; ci < 4; ++ci) {
      const int xb0 = ci * 1000 + vd * 100 + vh * 10 + vw;
#pragma unroll 1
      for (int t = 0; t < 27; ++t) {
        const int kd = t / 9, r9 = t - kd * 9;
        const int kh = r9 / 3, kw = r9 - kh * 3;
        const int off = kd * 100 + kh * 10 + kw;
        const float xv0 = ldsX[xb0 + off];
        const float xv1 = ldsX[xb0 + 400 + off];
        const float4* wp = reinterpret_cast<const float4*>(&ldsW[(ci * 27 + t) << 5]);
#pragma unroll
        for (int o4 = 0; o4 < 8; ++o4) {
          float4 w4 = wp[o4];
          acc0[o4 * 4 + 0] += xv0 * w4.x; acc1[o4 * 4 + 0] += xv1 * w4.x;
          acc0[o4 * 4 + 1] += xv0 * w4.y; acc1[o4 * 4 + 1] += xv1 * w4.y;
          acc0[o4 * 4 + 2] += xv0 * w4.z; acc1[o4 * 4 + 2] += xv1 * w4.z;
          acc0[o4 * 4 + 3] += xv0 * w4.w; acc1[o4 * 4 + 3] += xv1 * w4.w;
        }
      }
    }
  }

  const float* bias = bstack + (size_t)bcls * cls + co_base;
  const int gidx = (d0 + vd) * 1024 + (h0 + vh) * 32 + (w0 + vw);
  float* outb = out + (size_t)b * nco_total * S3 + (size_t)co_base * S3;
#pragma unroll
  for (int o = 0; o < 32; ++o) {
    float bb = bias[o];
    float v0 = acc0[o] + bb;
    float v1 = acc1[o] + bb;
    if (MODE == 0) { v0 = fmaxf(v0, 0.f); v1 = fmaxf(v1, 0.f); }
    float* po = outb + (size_t)o * S3;
    if (MODE == 2) {
      po[gidx] += v0;
      po[gidx + 4096] += v1;
    } else {
      po[gidx] = v0;
      po[gidx + 4096] = v1;
    }
  }
}

// ---------------------------------------------------------------- spade ----
// Fused gamma+beta conv (CIN=64 always) + SPADE epilogue + lrelu.
// Block: 8x8x8 tile, 16 channel-pairs (gamma & beta for same channels),
// co_base = blockIdx.z*16. NNORM = norm/out channel count (64 or 32).
template <int NNORM>
__global__ __launch_bounds__(256) void spade_kernel(
    const float* __restrict__ actv,      // [B][64][S3]
    const float* __restrict__ wg_stack,  // [NCLS][NNORM][64][27]
    const float* __restrict__ bg_stack,  // [NCLS][NNORM]
    const float* __restrict__ wb_stack,
    const float* __restrict__ bb_stack,
    const float* __restrict__ xnorm,     // [B][NNORM][S3]
    const float* __restrict__ mu,        // [B*NNORM]
    const float* __restrict__ rstd,      // [B*NNORM]
    const int* __restrict__ y,
    float* __restrict__ hout)            // [B][NNORM][S3]
{
  const int tid = threadIdx.x;
  const int b = blockIdx.y;
  const int cls = y[b];
  const int co_base = blockIdx.z * 16;
  const int tile = blockIdx.x;
  const int d0 = (tile >> 4) * 8, h0 = ((tile >> 2) & 3) * 8, w0 = (tile & 3) * 8;
  const int vd = tid >> 6, vh = (tid >> 3) & 7, vw = tid & 7;

  __shared__ float ldsX[4 * 1000];
  __shared__ float ldsWg[4 * 27 * 16];
  __shared__ float ldsWb[4 * 27 * 16];

  float ag0[16], ag1[16], ab0[16], ab1[16];
#pragma unroll
  for (int o = 0; o < 16; ++o) { ag0[o] = ag1[o] = ab0[o] = ab1[o] = 0.f; }

  const float* xin = actv + (size_t)b * 64 * S3;
  const long wstride = (long)NNORM * 64 * 27;
  const float* wgb = wg_stack + (size_t)wstride * cls + (size_t)co_base * 64 * 27;
  const float* wbb = wb_stack + (size_t)wstride * cls + (size_t)co_base * 64 * 27;

  for (int cg = 0; cg < 16; ++cg) {  // 64 input channels / 4
    __syncthreads();
    for (int i = tid; i < 4000; i += 256) {
      int ci = i / 1000, r = i - ci * 1000;
      int dd = r / 100; r -= dd * 100;
      int hh = r / 10;
      int ww = r - hh * 10;
      int gd = d0 + dd - 1, gh = h0 + hh - 1, gw = w0 + ww - 1;
      float v = 0.f;
      if ((unsigned)gd < 32u && (unsigned)gh < 32u && (unsigned)gw < 32u)
        v = xin[(size_t)(cg * 4 + ci) * S3 + gd * 1024 + gh * 32 + gw];
      ldsX[i] = v;
    }
    for (int i = tid; i < 4 * 27 * 16; i += 256) {
      int oc = i & 15, ct = i >> 4;
      int ci = ct / 27, t = ct - ci * 27;
      size_t gi = (size_t)oc * 64 * 27 + (size_t)(cg * 4 + ci) * 27 + t;
      ldsWg[i] = wgb[gi];
      ldsWb[i] = wbb[gi];
    }
    __syncthreads();

#pragma unroll
    for (int ci = 0; ci < 4; ++ci) {
      const int xb0 = ci * 1000 + vd * 100 + vh * 10 + vw;
#pragma unroll 1
      for (int t = 0; t < 27; ++t) {
        const int kd = t / 9, r9 = t - kd * 9;
        const int kh = r9 / 3, kw = r9 - kh * 3;
        const int off = kd * 100 + kh * 10 + kw;
        const float xv0 = ldsX[xb0 + off];
        const float xv1 = ldsX[xb0 + 400 + off];
        const float4* wpg = reinterpret_cast<const float4*>(&ldsWg[(ci * 27 + t) << 4]);
        const float4* wpb = reinterpret_cast<const float4*>(&ldsWb[(ci * 27 + t) << 4]);
#pragma unroll
        for (int o4 = 0; o4 < 4; ++o4) {
          float4 wg4 = wpg[o4];
          float4 wb4 = wpb[o4];
          ag0[o4 * 4 + 0] += xv0 * wg4.x; ag1[o4 * 4 + 0] += xv1 * wg4.x;
          ag0[o4 * 4 + 1] += xv0 * wg4.y; ag1[o4 * 4 + 1] += xv1 * wg4.y;
          ag0[o4 * 4 + 2] += xv0 * wg4.z; ag1[o4 * 4 + 2] += xv1 * wg4.z;
          ag0[o4 * 4 + 3] += xv0 * wg4.w; ag1[o4 * 4 + 3] += xv1 * wg4.w;
          ab0[o4 * 4 + 0] += xv0 * wb4.x; ab1[o4 * 4 + 0] += xv1 * wb4.x;
          ab0[o4 * 4 + 1] += xv0 * wb4.y; ab1[o4 * 4 + 1] += xv1 * wb4.y;
          ab0[o4 * 4 + 2] += xv0 * wb4.z; ab1[o4 * 4 + 2] += xv1 * wb4.z;
          ab0[o4 * 4 + 3] += xv0 * wb4.w; ab1[o4 * 4 + 3] += xv1 * wb4.w;
        }
      }
    }
  }

  const int gidx = (d0 + vd) * 1024 + (h0 + vh) * 32 + (w0 + vw);
#pragma unroll
  for (int o = 0; o < 16; ++o) {
    const int c = co_base + o;
    const float m = mu[b * NNORM + c];
    const float rs = rstd[b * NNORM + c];
    const float bg = bg_stack[(size_t)cls * NNORM + c];
    const float bb = bb_stack[(size_t)cls * NNORM + c];
    const float* xp = xnorm + ((size_t)b * NNORM + c) * S3;
    float* hp = hout + ((size_t)b * NNORM + c) * S3;

    float g0 = ag0[o] + bg, g1 = ag1[o] + bg;
    float t0 = ab0[o] + bb, t1 = ab1[o] + bb;
    float n0 = (xp[gidx] - m) * rs;
    float n1 = (xp[gidx + 4096] - m) * rs;
    float h0v = n0 * (1.f + g0) + t0;
    float h1v = n1 * (1.f + g1) + t1;
    h0v = h0v > 0.f ? h0v : 0.2f * h0v;
    h1v = h1v > 0.f ? h1v : 0.2f * h1v;
    hp[gidx] = h0v;
    hp[gidx + 4096] = h1v;
  }
}

// ------------------------------------------------------------- shortcut ----
// 1x1x1 conv 64 -> 32, no bias. Writes (initializes) d_out.
__global__ __launch_bounds__(256) void shortcut_kernel(const float* __restrict__ x,
                                                       const float* __restrict__ wsc,
                                                       float* __restrict__ out) {
  const int b = blockIdx.y;
  const int v = blockIdx.x * 256 + threadIdx.x;
  __shared__ float lw[64 * 32];  // [ci][oc]
  for (int i = threadIdx.x; i < 2048; i += 256) {
    int ci = i >> 5, o = i & 31;
    lw[i] = wsc[o * 64 + ci];
  }
  __syncthreads();
  float acc[32];
#pragma unroll
  for (int o = 0; o < 32; ++o) acc[o] = 0.f;
  const float* xp = x + (size_t)b * 64 * S3 + v;
#pragma unroll 1
  for (int ci = 0; ci < 64; ++ci) {
    const float xv = xp[(size_t)ci * S3];
    const float4* wp = reinterpret_cast<const float4*>(&lw[ci << 5]);
#pragma unroll
    for (int o4 = 0; o4 < 8; ++o4) {
      float4 w4 = wp[o4];
      acc[o4 * 4 + 0] += xv * w4.x;
      acc[o4 * 4 + 1] += xv * w4.y;
      acc[o4 * 4 + 2] += xv * w4.z;
      acc[o4 * 4 + 3] += xv * w4.w;
    }
  }
  float* op = out + (size_t)b * 32 * S3 + v;
#pragma unroll
  for (int o = 0; o < 32; ++o) op[(size_t)o * S3] = acc[o];
}

// ---------------------------------------------------------------- launch ---
extern "C" void kernel_launch(void* const* d_in, const int* in_sizes, int n_in,
                              void* d_out, int out_size, void* d_ws, size_t ws_size,
                              hipStream_t stream) {
  const float* x       = (const float*)d_in[0];
  const int*   y       = (const int*)d_in[1];
  const float* s0_ws   = (const float*)d_in[2];
  const float* s0_bs   = (const float*)d_in[3];
  const float* s0_wg   = (const float*)d_in[4];
  const float* s0_bg   = (const float*)d_in[5];
  const float* s0_wb   = (const float*)d_in[6];
  const float* s0_bb   = (const float*)d_in[7];
  const float* s1_ws   = (const float*)d_in[8];
  const float* s1_bs   = (const float*)d_in[9];
  const float* s1_wg   = (const float*)d_in[10];
  const float* s1_bg   = (const float*)d_in[11];
  const float* s1_wb   = (const float*)d_in[12];
  const float* s1_bb   = (const float*)d_in[13];
  const float* conv0_w = (const float*)d_in[14];
  const float* conv0_b = (const float*)d_in[15];
  const float* conv1_w = (const float*)d_in[16];
  const float* conv1_b = (const float*)d_in[17];
  const float* convs_w = (const float*)d_in[18];

  float* out = (float*)d_out;
  char* ws = (char*)d_ws;
  float* actv  = (float*)(ws);                 // [4][64][S3]  33.5 MB
  float* Hbuf  = (float*)(ws + 33554432);      // [4][64][S3]  33.5 MB
  float* D0    = (float*)(ws + 67108864);      // [4][32][S3]  16.8 MB
  float* stats = (float*)(ws + 83886080);      // mu0/rstd0/mu1/rstd1
  float* mu0 = stats, *rstd0 = stats + 256, *mu1 = stats + 512, *rstd1 = stats + 640;

  // 1. instance-norm stats of x (4*64 blocks)
  stats_kernel<<<dim3(256), dim3(256), 0, stream>>>(x, mu0, rstd0);
  // 2. actv0 = relu(conv3(x, s0_ws[y]) + s0_bs[y])   [B][64]
  conv3_kernel<64, 0><<<dim3(64, 4, 2), dim3(256), 0, stream>>>(
      x, s0_ws, (long)64 * 64 * 27, s0_bs, 64, y, actv, 64);
  // 3. h0 = lrelu(SPADE(x; actv0))                    [B][64]
  spade_kernel<64><<<dim3(64, 4, 4), dim3(256), 0, stream>>>(
      actv, s0_wg, s0_bg, s0_wb, s0_bb, x, mu0, rstd0, y, Hbuf);
  // 4. dx0 = conv3(h0, conv0_w) + conv0_b             [B][32]
  conv3_kernel<64, 1><<<dim3(64, 4, 1), dim3(256), 0, stream>>>(
      Hbuf, conv0_w, 0, conv0_b, 0, y, D0, 32);
  // 5. instance-norm stats of dx0 (4*32 blocks)
  stats_kernel<<<dim3(128), dim3(256), 0, stream>>>(D0, mu1, rstd1);
  // 6. actv1 = relu(conv3(dx0, s1_ws[y]) + s1_bs[y])  [B][64]
  conv3_kernel<32, 0><<<dim3(64, 4, 2), dim3(256), 0, stream>>>(
      D0, s1_ws, (long)64 * 32 * 27, s1_bs, 64, y, actv, 64);
  // 7. h1 = lrelu(SPADE(dx0; actv1))                  [B][32]
  spade_kernel<32><<<dim3(64, 4, 2), dim3(256), 0, stream>>>(
      actv, s1_wg, s1_bg, s1_wb, s1_bb, D0, mu1, rstd1, y, Hbuf);
  // 8. out = conv1x1(x, convs_w)
  shortcut_kernel<<<dim3(128, 4), dim3(256), 0, stream>>>(x, convs_w, out);
  // 9. out += conv3(h1, conv1_w) + conv1_b
  conv3_kernel<32, 2><<<dim3(64, 4, 1), dim3(256), 0, stream>>>(
      Hbuf, conv1_w, 0, conv1_b, 0, y, out, 32);
}

// Round 3
// 563.051 us; speedup vs baseline: 4.5826x; 4.5826x over previous
//
#include <hip/hip_runtime.h>

// SPADE ResNet block — bf16 MFMA implicit-GEMM implementation.
// B=4, FIN=64, FOUT=32, FMID=32, NCLS=4, NH=64, S=32 (S3=32768).
//
// Data layouts:
//   activations (bf16, "T layout"): [B][S3][C]   (channel-innermost)
//   weights repacked (bf16):        [B][27 taps][KC=CI/32][CO][32 ci]
//   conv = GEMM D[co][vox] = sum_tap sum_ci W_tap[co][ci] * Xshift_tap[ci][vox]
// MFMA 16x16x32 bf16: A = weights (co x ci), B = im2col (ci x vox).
// A-frag straight from global (L2-resident); B-frag via ds_read_b128 from a
// 6x10x10 padded LDS tile with rows padded to 40 shorts (80B) for bank spread.
//
// Round-2 bug fixed here: transpose_x phase-2 moved only 8 of 16 shorts per
// thread (uint4 = 8 bf16), leaving half of xt unwritten. Now copies 2x uint4.

#define S3 32768
constexpr float EPS = 1e-5f;

typedef __attribute__((ext_vector_type(8))) short s16x8;
typedef __attribute__((ext_vector_type(4))) float f32x4;
typedef __attribute__((ext_vector_type(4))) unsigned short u16x4;
typedef __attribute__((ext_vector_type(8))) unsigned short u16x8;

__device__ __forceinline__ float bf2f(unsigned short u) {
  union { unsigned int i; float f; } v; v.i = ((unsigned int)u) << 16; return v.f;
}
__device__ __forceinline__ unsigned short f2bf(float f) {
  union { float f; unsigned int i; } v; v.f = f;
  unsigned int r = (v.i + 0x7FFFu + ((v.i >> 16) & 1u)) >> 16;
  return (unsigned short)r;
}

// ---------------------------------------------------------------- stats ----
// One block per (b, c): mean + rstd over 32768 voxels of fp32 planar input.
__global__ __launch_bounds__(256) void stats_kernel(const float* __restrict__ x,
                                                    float* __restrict__ mu,
                                                    float* __restrict__ rstd) {
  const int bc = blockIdx.x;
  const float* p = x + (size_t)bc * S3;
  float s = 0.f, s2 = 0.f;
  for (int i = threadIdx.x; i < S3 / 4; i += 256) {
    float4 v = reinterpret_cast<const float4*>(p)[i];
    s  += v.x + v.y + v.z + v.w;
    s2 += v.x * v.x + v.y * v.y + v.z * v.z + v.w * v.w;
  }
  for (int off = 32; off; off >>= 1) {
    s  += __shfl_down(s, off, 64);
    s2 += __shfl_down(s2, off, 64);
  }
  __shared__ float ls[4], ls2[4];
  const int wid = threadIdx.x >> 6;
  if ((threadIdx.x & 63) == 0) { ls[wid] = s; ls2[wid] = s2; }
  __syncthreads();
  if (threadIdx.x == 0) {
    float S = 0.f, S2 = 0.f;
    for (int i = 0; i < 4; ++i) { S += ls[i]; S2 += ls2[i]; }
    const float m = S / (float)S3;
    const float var = S2 / (float)S3 - m * m;
    mu[bc] = m;
    rstd[bc] = rsqrtf(var + EPS);
  }
}

// Stats over bf16 T-layout tensor [B][S3][32] (dx0). One block per b.
__global__ __launch_bounds__(256) void stats_t32(const short* __restrict__ t,
                                                 float* __restrict__ mu,
                                                 float* __restrict__ rstd) {
  const int b = blockIdx.x;
  const int tid = threadIdx.x;
  const int part = tid & 3;              // 8-channel group
  float s[8], s2[8];
#pragma unroll
  for (int j = 0; j < 8; ++j) { s[j] = 0.f; s2[j] = 0.f; }
  for (int v = tid >> 2; v < S3; v += 64) {
    u16x8 u = *reinterpret_cast<const u16x8*>(&t[((size_t)b * S3 + v) * 32 + part * 8]);
#pragma unroll
    for (int j = 0; j < 8; ++j) { float f = bf2f(u[j]); s[j] += f; s2[j] += f * f; }
  }
#pragma unroll
  for (int off = 4; off < 64; off <<= 1) {
#pragma unroll
    for (int j = 0; j < 8; ++j) {
      s[j]  += __shfl_xor(s[j], off, 64);
      s2[j] += __shfl_xor(s2[j], off, 64);
    }
  }
  __shared__ float red[4][4][16];
  const int wv = tid >> 6, lane = tid & 63;
  if (lane < 4) {
#pragma unroll
    for (int j = 0; j < 8; ++j) { red[wv][lane][j] = s[j]; red[wv][lane][8 + j] = s2[j]; }
  }
  __syncthreads();
  if (tid < 32) {
    const int p = tid >> 3, j = tid & 7;
    float S = 0.f, S2 = 0.f;
    for (int w = 0; w < 4; ++w) { S += red[w][p][j]; S2 += red[w][p][8 + j]; }
    const float m = S / (float)S3;
    const float var = S2 / (float)S3 - m * m;
    mu[b * 32 + tid] = m;
    rstd[b * 32 + tid] = rsqrtf(var + EPS);
  }
}

// ------------------------------------------------------------ transpose ----
// x [B][64][S3] fp32 -> xt [B][S3][64] bf16.
__global__ __launch_bounds__(256) void transpose_x(const float* __restrict__ x,
                                                   short* __restrict__ xt) {
  const int b = blockIdx.y;
  const int v0 = blockIdx.x * 64;
  __shared__ unsigned short t[64][72];
  const int vox = threadIdx.x & 63;
  const int cg = threadIdx.x >> 6;
#pragma unroll
  for (int k = 0; k < 16; ++k) {
    const int ci = cg * 16 + k;
    t[vox][ci] = f2bf(x[((size_t)(b * 64 + ci)) * S3 + v0 + vox]);
  }
  __syncthreads();
  // each thread moves 16 shorts (32 B): two uint4 copies
  const int vv = threadIdx.x >> 2, part = threadIdx.x & 3;
  uint4 u0 = *reinterpret_cast<const uint4*>(&t[vv][part * 16]);
  uint4 u1 = *reinterpret_cast<const uint4*>(&t[vv][part * 16 + 8]);
  short* dst = &xt[((size_t)(b * S3 + v0 + vv)) * 64 + part * 16];
  *reinterpret_cast<uint4*>(dst) = u0;
  *reinterpret_cast<uint4*>(dst + 8) = u1;
}

// --------------------------------------------------------------- repack ----
// [cls][CO'][CI][27] fp32 (wA for co<CO_A, wB above) -> [b][27][KC][CO2][32] bf16
__global__ __launch_bounds__(256) void repack_w(
    const float* __restrict__ wA, const float* __restrict__ wB,
    short* __restrict__ dst, const int* __restrict__ y,
    int CO_A, int CO2, int CI, long clsA, long clsB, int total) {
  const int b = blockIdx.y;
  const int idx = blockIdx.x * 256 + threadIdx.x;
  if (idx >= total) return;
  const int cls = y[b];
  const int KC = CI / 32;
  const int ci = idx & 31;
  const int co = (idx >> 5) % CO2;
  const int rest = idx / (32 * CO2);
  const int kc = rest % KC;
  const int tap = rest / KC;
  float v;
  if (co < CO_A)
    v = wA[(size_t)clsA * cls + ((size_t)co * CI + kc * 32 + ci) * 27 + tap];
  else
    v = wB[(size_t)clsB * cls + ((size_t)(co - CO_A) * CI + kc * 32 + ci) * 27 + tap];
  dst[(((size_t)(b * 27 + tap) * KC + kc) * CO2 + co) * 32 + ci] = (short)f2bf(v);
}

// ------------------------------------------------------------ conv MFMA ----
// EPI: 0 relu+bias -> bf16 T   1 bias -> bf16 T
//      2 SPADE(NNORM=64, xnorm fp32 planar) -> bf16 T
//      3 SPADE(NNORM=32, xnorm bf16 T) -> bf16 T
//      4 bias + accumulate into fp32 planar out
template <int CIN, int CO, int EPI, int NNORM>
__global__ __launch_bounds__(256, 2) void conv_mfma(
    const short* __restrict__ xt,      // [B][S3][CIN] bf16
    const short* __restrict__ W,       // [B][27][KC][CO][32] bf16
    const float* __restrict__ bias,    // EPI 0/1/4
    int bias_stride,
    const int* __restrict__ y,
    const float* __restrict__ xnf,     // EPI2 planar fp32
    const short* __restrict__ xnb,     // EPI3 T bf16
    const float* __restrict__ mu,
    const float* __restrict__ rstd,
    const float* __restrict__ bgs,     // [NCLS][NNORM]
    const float* __restrict__ bbs,
    float* __restrict__ outf,          // EPI4
    short* __restrict__ outb) {        // EPI 0..3
  constexpr int KC = CIN / 32;
  constexpr int NCOG = CO / 16;
  const int tid = threadIdx.x;
  const int b = blockIdx.y;
  const int cls = y[b];
  const int tile = blockIdx.x;
  const int d0 = (tile >> 4) * 4, h0 = ((tile >> 2) & 3) * 8, w0 = (tile & 3) * 8;
  const int lane = tid & 63, wid = tid >> 6;
  const int kq = lane >> 4, l15 = lane & 15;
  const int dh = (lane >> 3) & 1, wv = lane & 7;

  __shared__ short lds[600 * 40];      // [6x10x10 padded voxels][40 (32 ci + pad)]

  f32x4 acc[4][NCOG];
  const f32x4 z4 = {0.f, 0.f, 0.f, 0.f};
#pragma unroll
  for (int v = 0; v < 4; ++v)
#pragma unroll
    for (int c = 0; c < NCOG; ++c) acc[v][c] = z4;

  const int base = (wid * 100 + dh * 10 + wv) * 40 + kq * 8;

  for (int kc = 0; kc < KC; ++kc) {
    __syncthreads();
    for (int i = tid; i < 2400; i += 256) {
      const int slot = i >> 2, part = i & 3;
      int pd = slot / 100; int r = slot - pd * 100;
      int ph = r / 10; int pw = r - ph * 10;
      const int gd = d0 + pd - 1, gh = h0 + ph - 1, gw = w0 + pw - 1;
      s16x8 v = {0, 0, 0, 0, 0, 0, 0, 0};
      if ((unsigned)gd < 32u && (unsigned)gh < 32u && (unsigned)gw < 32u)
        v = *reinterpret_cast<const s16x8*>(
            &xt[((size_t)b * S3 + gd * 1024 + gh * 32 + gw) * CIN + kc * 32 + part * 8]);
      *reinterpret_cast<s16x8*>(&lds[slot * 40 + part * 8]) = v;
    }
    __syncthreads();

#pragma unroll
    for (int kd = 0; kd < 3; ++kd)
#pragma unroll
      for (int kh = 0; kh < 3; ++kh)
#pragma unroll
        for (int kw = 0; kw < 3; ++kw) {
          const int toff = (kd * 100 + kh * 10 + kw) * 40;
          s16x8 bf[4];
#pragma unroll
          for (int vg = 0; vg < 4; ++vg)
            bf[vg] = *reinterpret_cast<const s16x8*>(&lds[base + vg * 800 + toff]);
          const int tap = kd * 9 + kh * 3 + kw;
          const short* wt = W + (((size_t)(b * 27 + tap) * KC + kc) * CO) * 32;
#pragma unroll
          for (int cog = 0; cog < NCOG; ++cog) {
            s16x8 af = *reinterpret_cast<const s16x8*>(&wt[(cog * 16 + l15) * 32 + kq * 8]);
#pragma unroll
            for (int vg = 0; vg < 4; ++vg)
              acc[vg][cog] =
                  __builtin_amdgcn_mfma_f32_16x16x32_bf16(af, bf[vg], acc[vg][cog], 0, 0, 0);
          }
        }
  }

  // epilogue. C-frag: col = lane&15 -> voxel, row = kq*4 + r -> co (within cog).
  const int gv = (d0 + wid) * 1024 + (h0 + dh) * 32 + (w0 + wv);   // vg adds vg*64

  if constexpr (EPI == 0 || EPI == 1) {
#pragma unroll
    for (int cog = 0; cog < NCOG; ++cog) {
      const int c0 = cog * 16 + kq * 4;
      const f32x4 b4 = *reinterpret_cast<const f32x4*>(&bias[cls * bias_stride + c0]);
#pragma unroll
      for (int vg = 0; vg < 4; ++vg) {
        u16x4 o;
#pragma unroll
        for (int r = 0; r < 4; ++r) {
          float v = acc[vg][cog][r] + b4[r];
          if constexpr (EPI == 0) v = fmaxf(v, 0.f);
          o[r] = f2bf(v);
        }
        *reinterpret_cast<u16x4*>(&outb[((size_t)b * S3 + gv + vg * 64) * CO + c0]) = o;
      }
    }
  }

  if constexpr (EPI == 2 || EPI == 3) {
    constexpr int NH2 = NNORM / 16;    // gamma co-groups; beta at cog+NH2
#pragma unroll
    for (int cog = 0; cog < NH2; ++cog) {
      const int c0 = cog * 16 + kq * 4;
      const f32x4 m4  = *reinterpret_cast<const f32x4*>(&mu[b * NNORM + c0]);
      const f32x4 r4  = *reinterpret_cast<const f32x4*>(&rstd[b * NNORM + c0]);
      const f32x4 g4  = *reinterpret_cast<const f32x4*>(&bgs[cls * NNORM + c0]);
      const f32x4 bb4 = *reinterpret_cast<const f32x4*>(&bbs[cls * NNORM + c0]);
#pragma unroll
      for (int vg = 0; vg < 4; ++vg) {
        const size_t vgl = (size_t)b * S3 + gv + vg * 64;
        f32x4 xn;
        if constexpr (EPI == 2) {
#pragma unroll
          for (int r = 0; r < 4; ++r)
            xn[r] = xnf[((size_t)(b * NNORM + c0 + r)) * S3 + gv + vg * 64];
        } else {
          u16x4 u = *reinterpret_cast<const u16x4*>(&xnb[vgl * 32 + c0]);
#pragma unroll
          for (int r = 0; r < 4; ++r) xn[r] = bf2f(u[r]);
        }
        u16x4 o;
#pragma unroll
        for (int r = 0; r < 4; ++r) {
          const float gamma = acc[vg][cog][r] + g4[r];
          const float beta  = acc[vg][cog + NH2][r] + bb4[r];
          const float nrm = (xn[r] - m4[r]) * r4[r];
          float h = nrm * (1.f + gamma) + beta;
          h = h > 0.f ? h : 0.2f * h;
          o[r] = f2bf(h);
        }
        *reinterpret_cast<u16x4*>(&outb[vgl * NNORM + c0]) = o;
      }
    }
  }

  if constexpr (EPI == 4) {
#pragma unroll
    for (int cog = 0; cog < NCOG; ++cog) {
      const int c0 = cog * 16 + kq * 4;
      const f32x4 b4 = *reinterpret_cast<const f32x4*>(&bias[c0]);
#pragma unroll
      for (int vg = 0; vg < 4; ++vg) {
#pragma unroll
        for (int r = 0; r < 4; ++r) {
          float* p = &outf[((size_t)(b * 32 + c0 + r)) * S3 + gv + vg * 64];
          *p += acc[vg][cog][r] + b4[r];
        }
      }
    }
  }
}

// ------------------------------------------------------------- shortcut ----
// 1x1x1 conv 64 -> 32, no bias, fp32 planar. Initializes d_out.
__global__ __launch_bounds__(256) void shortcut_kernel(const float* __restrict__ x,
                                                       const float* __restrict__ wsc,
                                                       float* __restrict__ out) {
  const int b = blockIdx.y;
  const int v = blockIdx.x * 256 + threadIdx.x;
  __shared__ float lw[64 * 32];  // [ci][oc]
  for (int i = threadIdx.x; i < 2048; i += 256) {
    int ci = i >> 5, o = i & 31;
    lw[i] = wsc[o * 64 + ci];
  }
  __syncthreads();
  float acc[32];
#pragma unroll
  for (int o = 0; o < 32; ++o) acc[o] = 0.f;
  const float* xp = x + (size_t)b * 64 * S3 + v;
#pragma unroll 1
  for (int ci = 0; ci < 64; ++ci) {
    const float xv = xp[(size_t)ci * S3];
    const float4* wp = reinterpret_cast<const float4*>(&lw[ci << 5]);
#pragma unroll
    for (int o4 = 0; o4 < 8; ++o4) {
      float4 w4 = wp[o4];
      acc[o4 * 4 + 0] += xv * w4.x;
      acc[o4 * 4 + 1] += xv * w4.y;
      acc[o4 * 4 + 2] += xv * w4.z;
      acc[o4 * 4 + 3] += xv * w4.w;
    }
  }
  float* op = out + (size_t)b * 32 * S3 + v;
#pragma unroll
  for (int o = 0; o < 32; ++o) op[(size_t)o * S3] = acc[o];
}

// ---------------------------------------------------------------- launch ---
extern "C" void kernel_launch(void* const* d_in, const int* in_sizes, int n_in,
                              void* d_out, int out_size, void* d_ws, size_t ws_size,
                              hipStream_t stream) {
  const float* x       = (const float*)d_in[0];
  const int*   y       = (const int*)d_in[1];
  const float* s0_ws   = (const float*)d_in[2];
  const float* s0_bs   = (const float*)d_in[3];
  const float* s0_wg   = (const float*)d_in[4];
  const float* s0_bg   = (const float*)d_in[5];
  const float* s0_wb   = (const float*)d_in[6];
  const float* s0_bb   = (const float*)d_in[7];
  const float* s1_ws   = (const float*)d_in[8];
  const float* s1_bs   = (const float*)d_in[9];
  const float* s1_wg   = (const float*)d_in[10];
  const float* s1_bg   = (const float*)d_in[11];
  const float* s1_wb   = (const float*)d_in[12];
  const float* s1_bb   = (const float*)d_in[13];
  const float* conv0_w = (const float*)d_in[14];
  const float* conv0_b = (const float*)d_in[15];
  const float* conv1_w = (const float*)d_in[16];
  const float* conv1_b = (const float*)d_in[17];
  const float* convs_w = (const float*)d_in[18];

  float* out = (float*)d_out;
  char* ws = (char*)d_ws;
  short* xt    = (short*)(ws);               // [4][S3][64] bf16  16.78 MB
  short* actvT = (short*)(ws + 16777216);    // [4][S3][64]       16.78 MB
  short* hT    = (short*)(ws + 33554432);    // [4][S3][<=64]     16.78 MB
  short* d0T   = (short*)(ws + 50331648);    // [4][S3][32]        8.39 MB
  short* Wa0   = (short*)(ws + 58720256);
  short* Ws0   = (short*)(ws + 60817408);
  short* Wc0   = (short*)(ws + 62914560);
  short* Wa1   = (short*)(ws + 65011712);
  short* Ws1   = (short*)(ws + 67108864);
  short* Wc1   = (short*)(ws + 69206016);
  float* stats = (float*)(ws + 71303168);
  float* mu0 = stats, *rstd0 = stats + 256, *mu1 = stats + 512, *rstd1 = stats + 640;

  // input transpose + instance-norm stats of x
  transpose_x<<<dim3(512, 4), 256, 0, stream>>>(x, xt);
  stats_kernel<<<dim3(256), 256, 0, stream>>>(x, mu0, rstd0);

  // weight repacks (per-b class selected), bf16
  repack_w<<<dim3(432, 4), 256, 0, stream>>>(s0_ws, s0_ws, Wa0, y, 64, 64, 64,
                                             64L * 64 * 27, 0, 110592);
  repack_w<<<dim3(864, 4), 256, 0, stream>>>(s0_wg, s0_wb, Ws0, y, 64, 128, 64,
                                             64L * 64 * 27, 64L * 64 * 27, 221184);
  repack_w<<<dim3(216, 4), 256, 0, stream>>>(conv0_w, conv0_w, Wc0, y, 32, 32, 64,
                                             0, 0, 55296);
  repack_w<<<dim3(216, 4), 256, 0, stream>>>(s1_ws, s1_ws, Wa1, y, 64, 64, 32,
                                             64L * 32 * 27, 0, 55296);
  repack_w<<<dim3(432, 4), 256, 0, stream>>>(s1_wg, s1_wb, Ws1, y, 32, 64, 64,
                                             32L * 64 * 27, 32L * 64 * 27, 110592);
  repack_w<<<dim3(108, 4), 256, 0, stream>>>(conv1_w, conv1_w, Wc1, y, 32, 32, 32,
                                             0, 0, 27648);

  // actv0 = relu(conv3(x, s0_ws) + s0_bs)          [B][S3][64]
  conv_mfma<64, 64, 0, 16><<<dim3(128, 4), 256, 0, stream>>>(
      xt, Wa0, s0_bs, 64, y, nullptr, nullptr, nullptr, nullptr, nullptr, nullptr,
      nullptr, actvT);
  // h0 = lrelu(SPADE0(x; actv0))                   [B][S3][64]
  conv_mfma<64, 128, 2, 64><<<dim3(128, 4), 256, 0, stream>>>(
      actvT, Ws0, nullptr, 0, y, x, nullptr, mu0, rstd0, s0_bg, s0_bb,
      nullptr, hT);
  // dx0 = conv3(h0, conv0_w) + conv0_b             [B][S3][32]
  conv_mfma<64, 32, 1, 16><<<dim3(128, 4), 256, 0, stream>>>(
      hT, Wc0, conv0_b, 0, y, nullptr, nullptr, nullptr, nullptr, nullptr, nullptr,
      nullptr, d0T);
  // instance-norm stats of dx0
  stats_t32<<<dim3(4), 256, 0, stream>>>(d0T, mu1, rstd1);
  // actv1 = relu(conv3(dx0, s1_ws) + s1_bs)        [B][S3][64]
  conv_mfma<32, 64, 0, 16><<<dim3(128, 4), 256, 0, stream>>>(
      d0T, Wa1, s1_bs, 64, y, nullptr, nullptr, nullptr, nullptr, nullptr, nullptr,
      nullptr, actvT);
  // h1 = lrelu(SPADE1(dx0; actv1))                 [B][S3][32]
  conv_mfma<64, 64, 3, 32><<<dim3(128, 4), 256, 0, stream>>>(
      actvT, Ws1, nullptr, 0, y, nullptr, d0T, mu1, rstd1, s1_bg, s1_bb,
      nullptr, hT);
  // out = conv1x1(x, convs_w)
  shortcut_kernel<<<dim3(128, 4), 256, 0, stream>>>(x, convs_w, out);
  // out += conv3(h1, conv1_w) + conv1_b
  conv_mfma<32, 32, 4, 16><<<dim3(128, 4), 256, 0, stream>>>(
      hT, Wc1, conv1_b, 0, y, nullptr, nullptr, nullptr, nullptr, nullptr, nullptr,
      out, nullptr);
}

// Round 4
// 426.441 us; speedup vs baseline: 6.0507x; 1.3203x over previous
//
#include <hip/hip_runtime.h>

// SPADE ResNet block — bf16 MFMA implicit-GEMM implementation.
// B=4, FIN=64, FOUT=32, FMID=32, NCLS=4, NH=64, S=32 (S3=32768).
//
// Round-4 change: stats_t32 (4-block, 150us, 0.17% occupancy) replaced by a
// two-phase deterministic reduction (256 blocks + 1 tiny block).

#define S3 32768
constexpr float EPS = 1e-5f;

typedef __attribute__((ext_vector_type(8))) short s16x8;
typedef __attribute__((ext_vector_type(4))) float f32x4;
typedef __attribute__((ext_vector_type(4))) unsigned short u16x4;
typedef __attribute__((ext_vector_type(8))) unsigned short u16x8;

__device__ __forceinline__ float bf2f(unsigned short u) {
  union { unsigned int i; float f; } v; v.i = ((unsigned int)u) << 16; return v.f;
}
__device__ __forceinline__ unsigned short f2bf(float f) {
  union { float f; unsigned int i; } v; v.f = f;
  unsigned int r = (v.i + 0x7FFFu + ((v.i >> 16) & 1u)) >> 16;
  return (unsigned short)r;
}

// ---------------------------------------------------------------- stats ----
// One block per (b, c): mean + rstd over 32768 voxels of fp32 planar input.
__global__ __launch_bounds__(256) void stats_kernel(const float* __restrict__ x,
                                                    float* __restrict__ mu,
                                                    float* __restrict__ rstd) {
  const int bc = blockIdx.x;
  const float* p = x + (size_t)bc * S3;
  float s = 0.f, s2 = 0.f;
  for (int i = threadIdx.x; i < S3 / 4; i += 256) {
    float4 v = reinterpret_cast<const float4*>(p)[i];
    s  += v.x + v.y + v.z + v.w;
    s2 += v.x * v.x + v.y * v.y + v.z * v.z + v.w * v.w;
  }
  for (int off = 32; off; off >>= 1) {
    s  += __shfl_down(s, off, 64);
    s2 += __shfl_down(s2, off, 64);
  }
  __shared__ float ls[4], ls2[4];
  const int wid = threadIdx.x >> 6;
  if ((threadIdx.x & 63) == 0) { ls[wid] = s; ls2[wid] = s2; }
  __syncthreads();
  if (threadIdx.x == 0) {
    float S = 0.f, S2 = 0.f;
    for (int i = 0; i < 4; ++i) { S += ls[i]; S2 += ls2[i]; }
    const float m = S / (float)S3;
    const float var = S2 / (float)S3 - m * m;
    mu[bc] = m;
    rstd[bc] = rsqrtf(var + EPS);
  }
}

// Stats over bf16 T-layout tensor [B][S3][32] (dx0), phase 1.
// grid (64, B): each block reduces 512 voxels x 32 ch -> part[b][chunk][64]
// (s in [0..31], s2 in [32..63]).
__global__ __launch_bounds__(256) void stats_t32_p1(const short* __restrict__ t,
                                                    float* __restrict__ part) {
  const int b = blockIdx.y;
  const int chunk = blockIdx.x;
  const int tid = threadIdx.x;
  const int pq = tid & 3;              // 8-channel group
  float s[8], s2[8];
#pragma unroll
  for (int j = 0; j < 8; ++j) { s[j] = 0.f; s2[j] = 0.f; }
  const int vbase = chunk * 512;
#pragma unroll
  for (int v = tid >> 2; v < 512; v += 64) {
    u16x8 u = *reinterpret_cast<const u16x8*>(
        &t[((size_t)b * S3 + vbase + v) * 32 + pq * 8]);
#pragma unroll
    for (int j = 0; j < 8; ++j) { float f = bf2f(u[j]); s[j] += f; s2[j] += f * f; }
  }
#pragma unroll
  for (int off = 4; off < 64; off <<= 1) {
#pragma unroll
    for (int j = 0; j < 8; ++j) {
      s[j]  += __shfl_xor(s[j], off, 64);
      s2[j] += __shfl_xor(s2[j], off, 64);
    }
  }
  __shared__ float red[4][4][16];
  const int wv = tid >> 6, lane = tid & 63;
  if (lane < 4) {
#pragma unroll
    for (int j = 0; j < 8; ++j) { red[wv][lane][j] = s[j]; red[wv][lane][8 + j] = s2[j]; }
  }
  __syncthreads();
  if (tid < 32) {
    const int p = tid >> 3, j = tid & 7;
    float S = 0.f, S2 = 0.f;
#pragma unroll
    for (int w = 0; w < 4; ++w) { S += red[w][p][j]; S2 += red[w][p][8 + j]; }
    const int c = p * 8 + j;
    part[((size_t)(b * 64 + chunk)) * 64 + c] = S;
    part[((size_t)(b * 64 + chunk)) * 64 + 32 + c] = S2;
  }
}

// phase 2: fold 64 partials -> mu/rstd. One block, 128 threads (b = t>>5).
__global__ __launch_bounds__(128) void stats_t32_p2(const float* __restrict__ part,
                                                    float* __restrict__ mu,
                                                    float* __restrict__ rstd) {
  const int tid = threadIdx.x;
  const int b = tid >> 5, c = tid & 31;
  float S = 0.f, S2 = 0.f;
#pragma unroll 4
  for (int k = 0; k < 64; ++k) {
    S  += part[((size_t)(b * 64 + k)) * 64 + c];
    S2 += part[((size_t)(b * 64 + k)) * 64 + 32 + c];
  }
  const float m = S / (float)S3;
  const float var = S2 / (float)S3 - m * m;
  mu[b * 32 + c] = m;
  rstd[b * 32 + c] = rsqrtf(var + EPS);
}

// ------------------------------------------------------------ transpose ----
// x [B][64][S3] fp32 -> xt [B][S3][64] bf16.
__global__ __launch_bounds__(256) void transpose_x(const float* __restrict__ x,
                                                   short* __restrict__ xt) {
  const int b = blockIdx.y;
  const int v0 = blockIdx.x * 64;
  __shared__ unsigned short t[64][72];
  const int vox = threadIdx.x & 63;
  const int cg = threadIdx.x >> 6;
#pragma unroll
  for (int k = 0; k < 16; ++k) {
    const int ci = cg * 16 + k;
    t[vox][ci] = f2bf(x[((size_t)(b * 64 + ci)) * S3 + v0 + vox]);
  }
  __syncthreads();
  // each thread moves 16 shorts (32 B): two uint4 copies
  const int vv = threadIdx.x >> 2, part = threadIdx.x & 3;
  uint4 u0 = *reinterpret_cast<const uint4*>(&t[vv][part * 16]);
  uint4 u1 = *reinterpret_cast<const uint4*>(&t[vv][part * 16 + 8]);
  short* dst = &xt[((size_t)(b * S3 + v0 + vv)) * 64 + part * 16];
  *reinterpret_cast<uint4*>(dst) = u0;
  *reinterpret_cast<uint4*>(dst + 8) = u1;
}

// --------------------------------------------------------------- repack ----
// [cls][CO'][CI][27] fp32 (wA for co<CO_A, wB above) -> [b][27][KC][CO2][32] bf16
__global__ __launch_bounds__(256) void repack_w(
    const float* __restrict__ wA, const float* __restrict__ wB,
    short* __restrict__ dst, const int* __restrict__ y,
    int CO_A, int CO2, int CI, long clsA, long clsB, int total) {
  const int b = blockIdx.y;
  const int idx = blockIdx.x * 256 + threadIdx.x;
  if (idx >= total) return;
  const int cls = y[b];
  const int KC = CI / 32;
  const int ci = idx & 31;
  const int co = (idx >> 5) % CO2;
  const int rest = idx / (32 * CO2);
  const int kc = rest % KC;
  const int tap = rest / KC;
  float v;
  if (co < CO_A)
    v = wA[(size_t)clsA * cls + ((size_t)co * CI + kc * 32 + ci) * 27 + tap];
  else
    v = wB[(size_t)clsB * cls + ((size_t)(co - CO_A) * CI + kc * 32 + ci) * 27 + tap];
  dst[(((size_t)(b * 27 + tap) * KC + kc) * CO2 + co) * 32 + ci] = (short)f2bf(v);
}

// ------------------------------------------------------------ conv MFMA ----
// EPI: 0 relu+bias -> bf16 T   1 bias -> bf16 T
//      2 SPADE(NNORM=64, xnorm fp32 planar) -> bf16 T
//      3 SPADE(NNORM=32, xnorm bf16 T) -> bf16 T
//      4 bias + accumulate into fp32 planar out
template <int CIN, int CO, int EPI, int NNORM>
__global__ __launch_bounds__(256, 2) void conv_mfma(
    const short* __restrict__ xt,      // [B][S3][CIN] bf16
    const short* __restrict__ W,       // [B][27][KC][CO][32] bf16
    const float* __restrict__ bias,    // EPI 0/1/4
    int bias_stride,
    const int* __restrict__ y,
    const float* __restrict__ xnf,     // EPI2 planar fp32
    const short* __restrict__ xnb,     // EPI3 T bf16
    const float* __restrict__ mu,
    const float* __restrict__ rstd,
    const float* __restrict__ bgs,     // [NCLS][NNORM]
    const float* __restrict__ bbs,
    float* __restrict__ outf,          // EPI4
    short* __restrict__ outb) {        // EPI 0..3
  constexpr int KC = CIN / 32;
  constexpr int NCOG = CO / 16;
  const int tid = threadIdx.x;
  const int b = blockIdx.y;
  const int cls = y[b];
  const int tile = blockIdx.x;
  const int d0 = (tile >> 4) * 4, h0 = ((tile >> 2) & 3) * 8, w0 = (tile & 3) * 8;
  const int lane = tid & 63, wid = tid >> 6;
  const int kq = lane >> 4, l15 = lane & 15;
  const int dh = (lane >> 3) & 1, wv = lane & 7;

  __shared__ short lds[600 * 40];      // [6x10x10 padded voxels][40 (32 ci + pad)]

  f32x4 acc[4][NCOG];
  const f32x4 z4 = {0.f, 0.f, 0.f, 0.f};
#pragma unroll
  for (int v = 0; v < 4; ++v)
#pragma unroll
    for (int c = 0; c < NCOG; ++c) acc[v][c] = z4;

  const int base = (wid * 100 + dh * 10 + wv) * 40 + kq * 8;

  for (int kc = 0; kc < KC; ++kc) {
    __syncthreads();
    for (int i = tid; i < 2400; i += 256) {
      const int slot = i >> 2, part = i & 3;
      int pd = slot / 100; int r = slot - pd * 100;
      int ph = r / 10; int pw = r - ph * 10;
      const int gd = d0 + pd - 1, gh = h0 + ph - 1, gw = w0 + pw - 1;
      s16x8 v = {0, 0, 0, 0, 0, 0, 0, 0};
      if ((unsigned)gd < 32u && (unsigned)gh < 32u && (unsigned)gw < 32u)
        v = *reinterpret_cast<const s16x8*>(
            &xt[((size_t)b * S3 + gd * 1024 + gh * 32 + gw) * CIN + kc * 32 + part * 8]);
      *reinterpret_cast<s16x8*>(&lds[slot * 40 + part * 8]) = v;
    }
    __syncthreads();

#pragma unroll
    for (int kd = 0; kd < 3; ++kd)
#pragma unroll
      for (int kh = 0; kh < 3; ++kh)
#pragma unroll
        for (int kw = 0; kw < 3; ++kw) {
          const int toff = (kd * 100 + kh * 10 + kw) * 40;
          s16x8 bf[4];
#pragma unroll
          for (int vg = 0; vg < 4; ++vg)
            bf[vg] = *reinterpret_cast<const s16x8*>(&lds[base + vg * 800 + toff]);
          const int tap = kd * 9 + kh * 3 + kw;
          const short* wt = W + (((size_t)(b * 27 + tap) * KC + kc) * CO) * 32;
#pragma unroll
          for (int cog = 0; cog < NCOG; ++cog) {
            s16x8 af = *reinterpret_cast<const s16x8*>(&wt[(cog * 16 + l15) * 32 + kq * 8]);
#pragma unroll
            for (int vg = 0; vg < 4; ++vg)
              acc[vg][cog] =
                  __builtin_amdgcn_mfma_f32_16x16x32_bf16(af, bf[vg], acc[vg][cog], 0, 0, 0);
          }
        }
  }

  // epilogue. C-frag: col = lane&15 -> voxel, row = kq*4 + r -> co (within cog).
  const int gv = (d0 + wid) * 1024 + (h0 + dh) * 32 + (w0 + wv);   // vg adds vg*64

  if constexpr (EPI == 0 || EPI == 1) {
#pragma unroll
    for (int cog = 0; cog < NCOG; ++cog) {
      const int c0 = cog * 16 + kq * 4;
      const f32x4 b4 = *reinterpret_cast<const f32x4*>(&bias[cls * bias_stride + c0]);
#pragma unroll
      for (int vg = 0; vg < 4; ++vg) {
        u16x4 o;
#pragma unroll
        for (int r = 0; r < 4; ++r) {
          float v = acc[vg][cog][r] + b4[r];
          if constexpr (EPI == 0) v = fmaxf(v, 0.f);
          o[r] = f2bf(v);
        }
        *reinterpret_cast<u16x4*>(&outb[((size_t)b * S3 + gv + vg * 64) * CO + c0]) = o;
      }
    }
  }

  if constexpr (EPI == 2 || EPI == 3) {
    constexpr int NH2 = NNORM / 16;    // gamma co-groups; beta at cog+NH2
#pragma unroll
    for (int cog = 0; cog < NH2; ++cog) {
      const int c0 = cog * 16 + kq * 4;
      const f32x4 m4  = *reinterpret_cast<const f32x4*>(&mu[b * NNORM + c0]);
      const f32x4 r4  = *reinterpret_cast<const f32x4*>(&rstd[b * NNORM + c0]);
      const f32x4 g4  = *reinterpret_cast<const f32x4*>(&bgs[cls * NNORM + c0]);
      const f32x4 bb4 = *reinterpret_cast<const f32x4*>(&bbs[cls * NNORM + c0]);
#pragma unroll
      for (int vg = 0; vg < 4; ++vg) {
        const size_t vgl = (size_t)b * S3 + gv + vg * 64;
        f32x4 xn;
        if constexpr (EPI == 2) {
#pragma unroll
          for (int r = 0; r < 4; ++r)
            xn[r] = xnf[((size_t)(b * NNORM + c0 + r)) * S3 + gv + vg * 64];
        } else {
          u16x4 u = *reinterpret_cast<const u16x4*>(&xnb[vgl * 32 + c0]);
#pragma unroll
          for (int r = 0; r < 4; ++r) xn[r] = bf2f(u[r]);
        }
        u16x4 o;
#pragma unroll
        for (int r = 0; r < 4; ++r) {
          const float gamma = acc[vg][cog][r] + g4[r];
          const float beta  = acc[vg][cog + NH2][r] + bb4[r];
          const float nrm = (xn[r] - m4[r]) * r4[r];
          float h = nrm * (1.f + gamma) + beta;
          h = h > 0.f ? h : 0.2f * h;
          o[r] = f2bf(h);
        }
        *reinterpret_cast<u16x4*>(&outb[vgl * NNORM + c0]) = o;
      }
    }
  }

  if constexpr (EPI == 4) {
#pragma unroll
    for (int cog = 0; cog < NCOG; ++cog) {
      const int c0 = cog * 16 + kq * 4;
      const f32x4 b4 = *reinterpret_cast<const f32x4*>(&bias[c0]);
#pragma unroll
      for (int vg = 0; vg < 4; ++vg) {
#pragma unroll
        for (int r = 0; r < 4; ++r) {
          float* p = &outf[((size_t)(b * 32 + c0 + r)) * S3 + gv + vg * 64];
          *p += acc[vg][cog][r] + b4[r];
        }
      }
    }
  }
}

// ------------------------------------------------------------- shortcut ----
// 1x1x1 conv 64 -> 32, no bias, fp32 planar. Initializes d_out.
__global__ __launch_bounds__(256) void shortcut_kernel(const float* __restrict__ x,
                                                       const float* __restrict__ wsc,
                                                       float* __restrict__ out) {
  const int b = blockIdx.y;
  const int v = blockIdx.x * 256 + threadIdx.x;
  __shared__ float lw[64 * 32];  // [ci][oc]
  for (int i = threadIdx.x; i < 2048; i += 256) {
    int ci = i >> 5, o = i & 31;
    lw[i] = wsc[o * 64 + ci];
  }
  __syncthreads();
  float acc[32];
#pragma unroll
  for (int o = 0; o < 32; ++o) acc[o] = 0.f;
  const float* xp = x + (size_t)b * 64 * S3 + v;
#pragma unroll 1
  for (int ci = 0; ci < 64; ++ci) {
    const float xv = xp[(size_t)ci * S3];
    const float4* wp = reinterpret_cast<const float4*>(&lw[ci << 5]);
#pragma unroll
    for (int o4 = 0; o4 < 8; ++o4) {
      float4 w4 = wp[o4];
      acc[o4 * 4 + 0] += xv * w4.x;
      acc[o4 * 4 + 1] += xv * w4.y;
      acc[o4 * 4 + 2] += xv * w4.z;
      acc[o4 * 4 + 3] += xv * w4.w;
    }
  }
  float* op = out + (size_t)b * 32 * S3 + v;
#pragma unroll
  for (int o = 0; o < 32; ++o) op[(size_t)o * S3] = acc[o];
}

// ---------------------------------------------------------------- launch ---
extern "C" void kernel_launch(void* const* d_in, const int* in_sizes, int n_in,
                              void* d_out, int out_size, void* d_ws, size_t ws_size,
                              hipStream_t stream) {
  const float* x       = (const float*)d_in[0];
  const int*   y       = (const int*)d_in[1];
  const float* s0_ws   = (const float*)d_in[2];
  const float* s0_bs   = (const float*)d_in[3];
  const float* s0_wg   = (const float*)d_in[4];
  const float* s0_bg   = (const float*)d_in[5];
  const float* s0_wb   = (const float*)d_in[6];
  const float* s0_bb   = (const float*)d_in[7];
  const float* s1_ws   = (const float*)d_in[8];
  const float* s1_bs   = (const float*)d_in[9];
  const float* s1_wg   = (const float*)d_in[10];
  const float* s1_bg   = (const float*)d_in[11];
  const float* s1_wb   = (const float*)d_in[12];
  const float* s1_bb   = (const float*)d_in[13];
  const float* conv0_w = (const float*)d_in[14];
  const float* conv0_b = (const float*)d_in[15];
  const float* conv1_w = (const float*)d_in[16];
  const float* conv1_b = (const float*)d_in[17];
  const float* convs_w = (const float*)d_in[18];

  float* out = (float*)d_out;
  char* ws = (char*)d_ws;
  short* xt    = (short*)(ws);               // [4][S3][64] bf16  16.78 MB
  short* actvT = (short*)(ws + 16777216);    // [4][S3][64]       16.78 MB
  short* hT    = (short*)(ws + 33554432);    // [4][S3][<=64]     16.78 MB
  short* d0T   = (short*)(ws + 50331648);    // [4][S3][32]        8.39 MB
  short* Wa0   = (short*)(ws + 58720256);
  short* Ws0   = (short*)(ws + 60817408);
  short* Wc0   = (short*)(ws + 62914560);
  short* Wa1   = (short*)(ws + 65011712);
  short* Ws1   = (short*)(ws + 67108864);
  short* Wc1   = (short*)(ws + 69206016);
  float* stats = (float*)(ws + 71303168);
  float* mu0 = stats, *rstd0 = stats + 256, *mu1 = stats + 512, *rstd1 = stats + 640;
  float* spart = stats + 1024;               // [4][64][64] partials (16K floats)

  // input transpose + instance-norm stats of x
  transpose_x<<<dim3(512, 4), 256, 0, stream>>>(x, xt);
  stats_kernel<<<dim3(256), 256, 0, stream>>>(x, mu0, rstd0);

  // weight repacks (per-b class selected), bf16
  repack_w<<<dim3(432, 4), 256, 0, stream>>>(s0_ws, s0_ws, Wa0, y, 64, 64, 64,
                                             64L * 64 * 27, 0, 110592);
  repack_w<<<dim3(864, 4), 256, 0, stream>>>(s0_wg, s0_wb, Ws0, y, 64, 128, 64,
                                             64L * 64 * 27, 64L * 64 * 27, 221184);
  repack_w<<<dim3(216, 4), 256, 0, stream>>>(conv0_w, conv0_w, Wc0, y, 32, 32, 64,
                                             0, 0, 55296);
  repack_w<<<dim3(216, 4), 256, 0, stream>>>(s1_ws, s1_ws, Wa1, y, 64, 64, 32,
                                             64L * 32 * 27, 0, 55296);
  repack_w<<<dim3(432, 4), 256, 0, stream>>>(s1_wg, s1_wb, Ws1, y, 32, 64, 64,
                                             32L * 64 * 27, 32L * 64 * 27, 110592);
  repack_w<<<dim3(108, 4), 256, 0, stream>>>(conv1_w, conv1_w, Wc1, y, 32, 32, 32,
                                             0, 0, 27648);

  // actv0 = relu(conv3(x, s0_ws) + s0_bs)          [B][S3][64]
  conv_mfma<64, 64, 0, 16><<<dim3(128, 4), 256, 0, stream>>>(
      xt, Wa0, s0_bs, 64, y, nullptr, nullptr, nullptr, nullptr, nullptr, nullptr,
      nullptr, actvT);
  // h0 = lrelu(SPADE0(x; actv0))                   [B][S3][64]
  conv_mfma<64, 128, 2, 64><<<dim3(128, 4), 256, 0, stream>>>(
      actvT, Ws0, nullptr, 0, y, x, nullptr, mu0, rstd0, s0_bg, s0_bb,
      nullptr, hT);
  // dx0 = conv3(h0, conv0_w) + conv0_b             [B][S3][32]
  conv_mfma<64, 32, 1, 16><<<dim3(128, 4), 256, 0, stream>>>(
      hT, Wc0, conv0_b, 0, y, nullptr, nullptr, nullptr, nullptr, nullptr, nullptr,
      nullptr, d0T);
  // instance-norm stats of dx0 (two-phase)
  stats_t32_p1<<<dim3(64, 4), 256, 0, stream>>>(d0T, spart);
  stats_t32_p2<<<dim3(1), 128, 0, stream>>>(spart, mu1, rstd1);
  // actv1 = relu(conv3(dx0, s1_ws) + s1_bs)        [B][S3][64]
  conv_mfma<32, 64, 0, 16><<<dim3(128, 4), 256, 0, stream>>>(
      d0T, Wa1, s1_bs, 64, y, nullptr, nullptr, nullptr, nullptr, nullptr, nullptr,
      nullptr, actvT);
  // h1 = lrelu(SPADE1(dx0; actv1))                 [B][S3][32]
  conv_mfma<64, 64, 3, 32><<<dim3(128, 4), 256, 0, stream>>>(
      actvT, Ws1, nullptr, 0, y, nullptr, d0T, mu1, rstd1, s1_bg, s1_bb,
      nullptr, hT);
  // out = conv1x1(x, convs_w)
  shortcut_kernel<<<dim3(128, 4), 256, 0, stream>>>(x, convs_w, out);
  // out += conv3(h1, conv1_w) + conv1_b
  conv_mfma<32, 32, 4, 16><<<dim3(128, 4), 256, 0, stream>>>(
      hT, Wc1, conv1_b, 0, y, nullptr, nullptr, nullptr, nullptr, nullptr, nullptr,
      out, nullptr);
}